// Round 1
// baseline (140.570 us; speedup 1.0000x reference)
//
#include <hip/hip_runtime.h>
#include <math.h>

// Problem constants (from setup_inputs): x is (32, 9, 256, 256) fp32.
#define BATCH 32
#define CHANS 9
#define HH 256
#define WW 256

// One wave (64 lanes x float4) spans one full row of 256 px.
// Each wave rolls through 8 output rows; block = 4 waves = 32-row strip.
__global__ __launch_bounds__(256) void edge_router_kernel(
    const float* __restrict__ x,
    const float* __restrict__ alpha_p,
    const float* __restrict__ scale_p,
    const int*   __restrict__ year,
    float* __restrict__ out)
{
    const int bid   = blockIdx.x;
    const int strip = bid & 7;        // 8 strips of 32 rows per plane
    const int plane = bid >> 3;       // b*CHANS + c
    const int b     = plane / CHANS;

    const int tid  = threadIdx.x;
    const int wave = tid >> 6;
    const int lane = tid & 63;

    const int y0 = strip * 32 + wave * 8;
    const int xq = lane * 4;

    const float* __restrict__ p = x   + (size_t)plane * (HH * WW);
    float*       __restrict__ q = out + (size_t)plane * (HH * WW);

    // ---- per-sample operator parameters (uniform across block) ----
    const int yr = year[b];
    float w0, w1, eps, post;
    if (yr == 2019) {            // sobel
        w0 = 1.f; w1 = 2.f; eps = 1e-8f; post = 1.f;
    } else if (yr == 2020) {     // scharr
        w0 = 3.f; w1 = 10.f; eps = 1e-8f; post = 1.f;
    } else {                     // learnable (2018, 2021)
        const float a = 1.f / (1.f + expf(-alpha_p[0]));
        const float m = 10.f - 8.f * a;          // max|kernel| element
        w0 = (3.f - 2.f * a) / m;
        w1 = 1.f;
        eps = 1e-6f;
        post = 1.f / (1.f + expf(-scale_p[0]));
    }

    // ---- helpers ----
    auto loadrow = [&](int y) -> float4 {
        if (y < 0 || y >= HH) return make_float4(0.f, 0.f, 0.f, 0.f);
        return *reinterpret_cast<const float4*>(p + (size_t)y * WW + xq);
    };

    // derive horizontal diff (for gx) and horizontal smooth (for gy) of a row
    auto derive = [&](float4 v, float4& d, float4& s) {
        float left  = __shfl_up(v.w, 1);
        if (lane == 0)  left  = 0.f;               // zero padding at x=-1
        float right = __shfl_down(v.x, 1);
        if (lane == 63) right = 0.f;               // zero padding at x=W
        d.x = v.y - left;  d.y = v.z - v.x;
        d.z = v.w - v.y;   d.w = right - v.z;
        s.x = fmaf(w1, v.x, w0 * (left + v.y));
        s.y = fmaf(w1, v.y, w0 * (v.x + v.z));
        s.z = fmaf(w1, v.z, w0 * (v.y + v.w));
        s.w = fmaf(w1, v.w, w0 * (v.z + right));
    };

    // ---- rolling 3-row pipeline ----
    float4 dm, sm, d0, s0v;
    {
        float4 vm = loadrow(y0 - 1);
        float4 v0 = loadrow(y0);
        derive(vm, dm, sm);
        derive(v0, d0, s0v);
    }

    #pragma unroll
    for (int r = 0; r < 8; ++r) {
        const int y = y0 + r;
        float4 vp = loadrow(y + 1);
        float4 dp, sp;
        derive(vp, dp, sp);

        float4 o;
        {
            float gx = fmaf(w1, d0.x, w0 * (dm.x + dp.x));
            float gy = sp.x - sm.x;
            o.x = sqrtf(fmaf(gx, gx, fmaf(gy, gy, eps))) * post;
        }
        {
            float gx = fmaf(w1, d0.y, w0 * (dm.y + dp.y));
            float gy = sp.y - sm.y;
            o.y = sqrtf(fmaf(gx, gx, fmaf(gy, gy, eps))) * post;
        }
        {
            float gx = fmaf(w1, d0.z, w0 * (dm.z + dp.z));
            float gy = sp.z - sm.z;
            o.z = sqrtf(fmaf(gx, gx, fmaf(gy, gy, eps))) * post;
        }
        {
            float gx = fmaf(w1, d0.w, w0 * (dm.w + dp.w));
            float gy = sp.w - sm.w;
            o.w = sqrtf(fmaf(gx, gx, fmaf(gy, gy, eps))) * post;
        }

        *reinterpret_cast<float4*>(q + (size_t)y * WW + xq) = o;

        dm = d0; sm = s0v;
        d0 = dp; s0v = sp;
    }
}

extern "C" void kernel_launch(void* const* d_in, const int* in_sizes, int n_in,
                              void* d_out, int out_size, void* d_ws, size_t ws_size,
                              hipStream_t stream) {
    const float* x     = (const float*)d_in[0];
    const float* alpha = (const float*)d_in[1];
    const float* scale = (const float*)d_in[2];
    const int*   year  = (const int*)  d_in[3];
    float* out = (float*)d_out;

    const int blocks = BATCH * CHANS * (HH / 32);   // 2304
    edge_router_kernel<<<blocks, 256, 0, stream>>>(x, alpha, scale, year, out);
}

// Round 3
// 136.752 us; speedup vs baseline: 1.0279x; 1.0279x over previous
//
#include <hip/hip_runtime.h>
#include <math.h>

// Problem constants (from setup_inputs): x is (32, 9, 256, 256) fp32.
#define BATCH 32
#define CHANS 9
#define HH 256
#define WW 256

typedef float f32x4 __attribute__((ext_vector_type(4)));

// One wave (64 lanes x float4) spans one full row of 256 px.
// Each wave computes 8 output rows; all 10 source rows are loaded upfront
// (unconditional, clamped addresses) to maximize memory-level parallelism.
// Block = 4 waves = 32-row strip.
__global__ __launch_bounds__(256) void edge_router_kernel(
    const float* __restrict__ x,
    const float* __restrict__ alpha_p,
    const float* __restrict__ scale_p,
    const int*   __restrict__ year,
    float* __restrict__ out)
{
    const int bid   = blockIdx.x;
    const int strip = bid & 7;        // 8 strips of 32 rows per plane
    const int plane = bid >> 3;       // b*CHANS + c
    const int b     = plane / CHANS;

    const int tid  = threadIdx.x;
    const int wave = tid >> 6;
    const int lane = tid & 63;

    const int y0 = strip * 32 + wave * 8;
    const int xq = lane * 4;

    const float* __restrict__ p = x   + (size_t)plane * (HH * WW);
    float*       __restrict__ q = out + (size_t)plane * (HH * WW);

    // ---- per-sample operator parameters (uniform across block) ----
    const int yr = year[b];
    float w0, w1, eps, post;
    if (yr == 2019) {            // sobel
        w0 = 1.f; w1 = 2.f; eps = 1e-8f; post = 1.f;
    } else if (yr == 2020) {     // scharr
        w0 = 3.f; w1 = 10.f; eps = 1e-8f; post = 1.f;
    } else {                     // learnable (2018, 2021)
        const float a = 1.f / (1.f + expf(-alpha_p[0]));
        const float m = 10.f - 8.f * a;          // max|kernel| element
        w0 = (3.f - 2.f * a) / m;
        w1 = 1.f;
        eps = 1e-6f;
        post = 1.f / (1.f + expf(-scale_p[0]));
    }

    // ---- load ALL 10 rows upfront, unconditionally (clamped) ----
    f32x4 v[10];
    #pragma unroll
    for (int i = 0; i < 10; ++i) {
        int y  = y0 - 1 + i;
        int yc = min(max(y, 0), HH - 1);
        v[i] = *reinterpret_cast<const f32x4*>(p + (size_t)yc * WW + xq);
    }
    // zero-pad rows outside the image (wave-uniform, only top/bottom strips)
    if (y0 == 0)       v[0] = (f32x4)0.f;
    if (y0 + 8 == HH)  v[9] = (f32x4)0.f;

    // derive horizontal diff (for gx) and horizontal smooth (for gy) of a row
    auto derive = [&](f32x4 vv, f32x4& d, f32x4& s) {
        float left  = __shfl_up(vv.w, 1);
        if (lane == 0)  left  = 0.f;               // zero padding at x=-1
        float right = __shfl_down(vv.x, 1);
        if (lane == 63) right = 0.f;               // zero padding at x=W
        d.x = vv.y - left;  d.y = vv.z - vv.x;
        d.z = vv.w - vv.y;  d.w = right - vv.z;
        s.x = fmaf(w1, vv.x, w0 * (left + vv.y));
        s.y = fmaf(w1, vv.y, w0 * (vv.x + vv.z));
        s.z = fmaf(w1, vv.z, w0 * (vv.y + vv.w));
        s.w = fmaf(w1, vv.w, w0 * (vv.z + right));
    };

    // ---- rolling 3-row window over the preloaded registers ----
    f32x4 dm, sm, d0, s0v;
    derive(v[0], dm, sm);
    derive(v[1], d0, s0v);

    #pragma unroll
    for (int r = 0; r < 8; ++r) {
        f32x4 dp, sp;
        derive(v[r + 2], dp, sp);

        f32x4 o;
        {
            float gx = fmaf(w1, d0.x, w0 * (dm.x + dp.x));
            float gy = sp.x - sm.x;
            o.x = sqrtf(fmaf(gx, gx, fmaf(gy, gy, eps))) * post;
        }
        {
            float gx = fmaf(w1, d0.y, w0 * (dm.y + dp.y));
            float gy = sp.y - sm.y;
            o.y = sqrtf(fmaf(gx, gx, fmaf(gy, gy, eps))) * post;
        }
        {
            float gx = fmaf(w1, d0.z, w0 * (dm.z + dp.z));
            float gy = sp.z - sm.z;
            o.z = sqrtf(fmaf(gx, gx, fmaf(gy, gy, eps))) * post;
        }
        {
            float gx = fmaf(w1, d0.w, w0 * (dm.w + dp.w));
            float gy = sp.w - sm.w;
            o.w = sqrtf(fmaf(gx, gx, fmaf(gy, gy, eps))) * post;
        }

        // write-only output: nontemporal store keeps L2 for the halo reads
        __builtin_nontemporal_store(o, reinterpret_cast<f32x4*>(q + (size_t)(y0 + r) * WW + xq));

        dm = d0; sm = s0v;
        d0 = dp; s0v = sp;
    }
}

extern "C" void kernel_launch(void* const* d_in, const int* in_sizes, int n_in,
                              void* d_out, int out_size, void* d_ws, size_t ws_size,
                              hipStream_t stream) {
    const float* x     = (const float*)d_in[0];
    const float* alpha = (const float*)d_in[1];
    const float* scale = (const float*)d_in[2];
    const int*   year  = (const int*)  d_in[3];
    float* out = (float*)d_out;

    const int blocks = BATCH * CHANS * (HH / 32);   // 2304
    edge_router_kernel<<<blocks, 256, 0, stream>>>(x, alpha, scale, year, out);
}

// Round 4
// 133.814 us; speedup vs baseline: 1.0505x; 1.0220x over previous
//
#include <hip/hip_runtime.h>
#include <math.h>

// Problem constants (from setup_inputs): x is (32, 9, 256, 256) fp32.
#define BATCH 32
#define CHANS 9
#define HH 256
#define WW 256

typedef float f32x4 __attribute__((ext_vector_type(4)));

// One wave (64 lanes x float4) = one full output row (256 px).
// 3 independent row loads -> one wait -> compute -> one store. No rolling
// window, no serial dependency chain; TLP = 73728 waves total.
__global__ __launch_bounds__(256) void edge_router_kernel(
    const float* __restrict__ x,
    const float* __restrict__ alpha_p,
    const float* __restrict__ scale_p,
    const int*   __restrict__ year,
    float* __restrict__ out)
{
    const int tid   = threadIdx.x;
    const int lane  = tid & 63;
    // global wave id == global row id across the whole (B*C, H) row space
    const int gwave = blockIdx.x * 4 + (tid >> 6);
    const int row   = gwave & (HH - 1);
    const int plane = gwave >> 8;           // b*CHANS + c
    const int b     = plane / CHANS;
    const int xq    = lane * 4;

    const float* __restrict__ p = x   + (size_t)plane * (HH * WW);
    float*       __restrict__ q = out + (size_t)plane * (HH * WW);

    // ---- 3 independent row loads, all in flight at once ----
    const int ym = row > 0 ? row - 1 : 0;
    const int yp = row < HH - 1 ? row + 1 : HH - 1;
    f32x4 vm = *reinterpret_cast<const f32x4*>(p + (size_t)ym  * WW + xq);
    f32x4 v0 = *reinterpret_cast<const f32x4*>(p + (size_t)row * WW + xq);
    f32x4 vp = *reinterpret_cast<const f32x4*>(p + (size_t)yp  * WW + xq);
    if (row == 0)      vm = (f32x4)0.f;   // wave-uniform zero padding
    if (row == HH - 1) vp = (f32x4)0.f;

    // ---- per-sample operator parameters (uniform across wave) ----
    const int yr = year[b];
    float w0, w1, eps, post;
    if (yr == 2019) {            // sobel
        w0 = 1.f; w1 = 2.f; eps = 1e-8f; post = 1.f;
    } else if (yr == 2020) {     // scharr
        w0 = 3.f; w1 = 10.f; eps = 1e-8f; post = 1.f;
    } else {                     // learnable (2018, 2021)
        const float a = 1.f / (1.f + expf(-alpha_p[0]));
        const float m = 10.f - 8.f * a;          // max|kernel| element
        w0 = (3.f - 2.f * a) / m;
        w1 = 1.f;
        eps = 1e-6f;
        post = 1.f / (1.f + expf(-scale_p[0]));
    }

    // derive horizontal diff (for gx) and horizontal smooth (for gy) of a row
    auto derive = [&](f32x4 vv, f32x4& d, f32x4& s) {
        float left  = __shfl_up(vv.w, 1);
        if (lane == 0)  left  = 0.f;               // zero padding at x=-1
        float right = __shfl_down(vv.x, 1);
        if (lane == 63) right = 0.f;               // zero padding at x=W
        d.x = vv.y - left;  d.y = vv.z - vv.x;
        d.z = vv.w - vv.y;  d.w = right - vv.z;
        s.x = fmaf(w1, vv.x, w0 * (left + vv.y));
        s.y = fmaf(w1, vv.y, w0 * (vv.x + vv.z));
        s.z = fmaf(w1, vv.z, w0 * (vv.y + vv.w));
        s.w = fmaf(w1, vv.w, w0 * (vv.z + right));
    };

    f32x4 dm, sm, d0, s0v, dp, sp;
    derive(vm, dm, sm);
    derive(v0, d0, s0v);
    derive(vp, dp, sp);

    f32x4 o;
    {
        float gx = fmaf(w1, d0.x, w0 * (dm.x + dp.x));
        float gy = sp.x - sm.x;
        o.x = sqrtf(fmaf(gx, gx, fmaf(gy, gy, eps))) * post;
    }
    {
        float gx = fmaf(w1, d0.y, w0 * (dm.y + dp.y));
        float gy = sp.y - sm.y;
        o.y = sqrtf(fmaf(gx, gx, fmaf(gy, gy, eps))) * post;
    }
    {
        float gx = fmaf(w1, d0.z, w0 * (dm.z + dp.z));
        float gy = sp.z - sm.z;
        o.z = sqrtf(fmaf(gx, gx, fmaf(gy, gy, eps))) * post;
    }
    {
        float gx = fmaf(w1, d0.w, w0 * (dm.w + dp.w));
        float gy = sp.w - sm.w;
        o.w = sqrtf(fmaf(gx, gx, fmaf(gy, gy, eps))) * post;
    }

    *reinterpret_cast<f32x4*>(q + (size_t)row * WW + xq) = o;
}

extern "C" void kernel_launch(void* const* d_in, const int* in_sizes, int n_in,
                              void* d_out, int out_size, void* d_ws, size_t ws_size,
                              hipStream_t stream) {
    const float* x     = (const float*)d_in[0];
    const float* alpha = (const float*)d_in[1];
    const float* scale = (const float*)d_in[2];
    const int*   year  = (const int*)  d_in[3];
    float* out = (float*)d_out;

    const int rows   = BATCH * CHANS * HH;      // 73728 waves, 1 row each
    const int blocks = rows / 4;                // 4 waves per block = 18432
    edge_router_kernel<<<blocks, 256, 0, stream>>>(x, alpha, scale, year, out);
}

// Round 5
// 132.289 us; speedup vs baseline: 1.0626x; 1.0115x over previous
//
#include <hip/hip_runtime.h>
#include <math.h>

// Problem constants (from setup_inputs): x is (32, 9, 256, 256) fp32.
#define BATCH 32
#define CHANS 9
#define HH 256
#define WW 256

typedef float f32x4 __attribute__((ext_vector_type(4)));

// One wave (64 lanes x float4 = 256 px) computes TWO adjacent output rows.
// Separable conv done vertical-first: t = vertical smooth, u = vertical diff
// (pure VALU, no cross-lane), then one horizontal shuffle pass per term.
// 4 row loads -> 2 output rows; 36864 waves total.
__global__ __launch_bounds__(256) void edge_router_kernel(
    const float* __restrict__ x,
    const float* __restrict__ alpha_p,
    const float* __restrict__ scale_p,
    const int*   __restrict__ year,
    float* __restrict__ out)
{
    const int tid   = threadIdx.x;
    const int lane  = tid & 63;
    const int gwave = blockIdx.x * 4 + (tid >> 6);
    const int pair  = gwave & 127;          // 128 row-pairs per plane
    const int plane = gwave >> 7;           // b*CHANS + c
    const int b     = plane / CHANS;
    const int r0    = pair * 2;
    const int r1    = r0 + 1;
    const int xq    = lane * 4;

    const float* __restrict__ p = x   + (size_t)plane * (HH * WW);
    float*       __restrict__ q = out + (size_t)plane * (HH * WW);

    // ---- 4 independent row loads (r0-1, r0, r1, r1+1), all in flight ----
    const int ym = r0 > 0 ? r0 - 1 : 0;
    const int yp = r1 < HH - 1 ? r1 + 1 : HH - 1;
    f32x4 va = *reinterpret_cast<const f32x4*>(p + (size_t)ym * WW + xq);
    f32x4 vb = *reinterpret_cast<const f32x4*>(p + (size_t)r0 * WW + xq);
    f32x4 vc = *reinterpret_cast<const f32x4*>(p + (size_t)r1 * WW + xq);
    f32x4 vd = *reinterpret_cast<const f32x4*>(p + (size_t)yp * WW + xq);
    if (r0 == 0)      va = (f32x4)0.f;   // wave-uniform zero padding
    if (r1 == HH - 1) vd = (f32x4)0.f;

    // ---- per-sample operator parameters (uniform across wave) ----
    const int yr = year[b];
    float w0, w1, eps, post;
    if (yr == 2019) {            // sobel
        w0 = 1.f; w1 = 2.f; eps = 1e-8f; post = 1.f;
    } else if (yr == 2020) {     // scharr
        w0 = 3.f; w1 = 10.f; eps = 1e-8f; post = 1.f;
    } else {                     // learnable (2018, 2021)
        const float a = 1.f / (1.f + expf(-alpha_p[0]));
        const float m = 10.f - 8.f * a;          // max|kernel| element
        w0 = (3.f - 2.f * a) / m;
        w1 = 1.f;
        eps = 1e-6f;
        post = 1.f / (1.f + expf(-scale_p[0]));
    }

    // horizontal pass + magnitude for one output row, given vertical terms
    auto finish_row = [&](f32x4 t, f32x4 u, int y) {
        // halo exchange (one shuffle pair per term)
        float tl = __shfl_up(t.w, 1);
        float ul = __shfl_up(u.w, 1);
        if (lane == 0)  { tl = 0.f; ul = 0.f; }    // zero pad x=-1
        float tr = __shfl_down(t.x, 1);
        float ur = __shfl_down(u.x, 1);
        if (lane == 63) { tr = 0.f; ur = 0.f; }    // zero pad x=W

        f32x4 gx, gy;
        gx.x = t.y - tl;   gx.y = t.z - t.x;
        gx.z = t.w - t.y;  gx.w = tr - t.z;
        gy.x = fmaf(w1, u.x, w0 * (ul + u.y));
        gy.y = fmaf(w1, u.y, w0 * (u.x + u.z));
        gy.z = fmaf(w1, u.z, w0 * (u.y + u.w));
        gy.w = fmaf(w1, u.w, w0 * (u.z + ur));

        f32x4 o;
        o.x = sqrtf(fmaf(gx.x, gx.x, fmaf(gy.x, gy.x, eps))) * post;
        o.y = sqrtf(fmaf(gx.y, gx.y, fmaf(gy.y, gy.y, eps))) * post;
        o.z = sqrtf(fmaf(gx.z, gx.z, fmaf(gy.z, gy.z, eps))) * post;
        o.w = sqrtf(fmaf(gx.w, gx.w, fmaf(gy.w, gy.w, eps))) * post;

        *reinterpret_cast<f32x4*>(q + (size_t)y * WW + xq) = o;
    };

    // ---- vertical terms (pure VALU, no cross-lane) ----
    f32x4 t0, u0, t1, u1;
    t0.x = fmaf(w1, vb.x, w0 * (va.x + vc.x));
    t0.y = fmaf(w1, vb.y, w0 * (va.y + vc.y));
    t0.z = fmaf(w1, vb.z, w0 * (va.z + vc.z));
    t0.w = fmaf(w1, vb.w, w0 * (va.w + vc.w));
    u0 = vc - va;
    t1.x = fmaf(w1, vc.x, w0 * (vb.x + vd.x));
    t1.y = fmaf(w1, vc.y, w0 * (vb.y + vd.y));
    t1.z = fmaf(w1, vc.z, w0 * (vb.z + vd.z));
    t1.w = fmaf(w1, vc.w, w0 * (vb.w + vd.w));
    u1 = vd - vb;

    finish_row(t0, u0, r0);
    finish_row(t1, u1, r1);
}

extern "C" void kernel_launch(void* const* d_in, const int* in_sizes, int n_in,
                              void* d_out, int out_size, void* d_ws, size_t ws_size,
                              hipStream_t stream) {
    const float* x     = (const float*)d_in[0];
    const float* alpha = (const float*)d_in[1];
    const float* scale = (const float*)d_in[2];
    const int*   year  = (const int*)  d_in[3];
    float* out = (float*)d_out;

    const int pairs  = BATCH * CHANS * (HH / 2);   // 36864 waves, 2 rows each
    const int blocks = pairs / 4;                  // 4 waves/block = 9216
    edge_router_kernel<<<blocks, 256, 0, stream>>>(x, alpha, scale, year, out);
}